// Round 2
// baseline (511.241 us; speedup 1.0000x reference)
//
#include <hip/hip_runtime.h>

#define B_ 8
#define S_ 1025
#define D_ 768
#define H_ 12
#define KV_ 4
#define HD_ 64
#define NREP 3
#define SCALE_ 0.125f
#define EPS_ 1e-6f
#define SKP 1088   // padded key count (17*64)
#define SCS 1092   // LDS score row stride in floats (16B-aligned rows)
#define QBLK 8     // q-rows per block
#define NQT 129    // ceil(1025/8)
#define NKT 17     // key tiles of 64

typedef __attribute__((ext_vector_type(8))) short bf16x8;
typedef __attribute__((ext_vector_type(4))) float f32x4;

__device__ __forceinline__ unsigned short f2bf(float f) {
  unsigned int u = __builtin_bit_cast(unsigned int, f);
  return (unsigned short)((u + 0x7FFFu + ((u >> 16) & 1u)) >> 16);
}
__device__ __forceinline__ unsigned int pk2(float a, float b) {
  return (unsigned int)f2bf(a) | ((unsigned int)f2bf(b) << 16);
}

// ---------------- casts ----------------
__global__ __launch_bounds__(256) void cast_x_kernel(const float* __restrict__ x,
                                                     unsigned short* __restrict__ xb, int n4) {
  int i = blockIdx.x * 256 + threadIdx.x;
  if (i >= n4) return;
  f32x4 v = *(const f32x4*)(x + (size_t)i * 4);
  uint2 o;
  o.x = pk2(v[0], v[1]);
  o.y = pk2(v[2], v[3]);
  *(uint2*)(xb + (size_t)i * 4) = o;
}

__global__ __launch_bounds__(256) void cast_wqkv_kernel(const float* __restrict__ Wq,
    const float* __restrict__ Wk, const float* __restrict__ Wv,
    unsigned short* __restrict__ WT) {
  int idx = blockIdx.x * 256 + threadIdx.x;  // = n*768 + k
  int n = idx / D_, k = idx % D_;
  float v;
  if (n < 768)       v = Wq[(size_t)k * 768 + n];
  else if (n < 1024) v = Wk[(size_t)k * 256 + (n - 768)];
  else               v = Wv[(size_t)k * 256 + (n - 1024)];
  WT[idx] = f2bf(v);
}

__global__ __launch_bounds__(256) void cast_wo_kernel(const float* __restrict__ Wo,
                                                      unsigned short* __restrict__ WT) {
  int idx = blockIdx.x * 256 + threadIdx.x;  // = n*768 + k
  int n = idx / D_, k = idx % D_;
  WT[idx] = f2bf(Wo[(size_t)k * D_ + n]);
}

// ---------------- GEMM: C[M][N] fp32 = A[M][K] bf16 @ BT[N][K] bf16 ----------------
#define BM 128
#define BN 128
#define BK 32
#define LSTR 40   // padded LDS row stride (ushorts): 80B = 20 banks -> 2-way max
__global__ __launch_bounds__(256) void gemm_bt(const unsigned short* __restrict__ A,
    const unsigned short* __restrict__ BT, float* __restrict__ C, int M, int N, int K) {
  __shared__ unsigned short As[BM * LSTR];
  __shared__ unsigned short Bs[BN * LSTR];
  const int nMt = (M + BM - 1) / BM;
  const int tm = blockIdx.x % nMt;
  const int tn = blockIdx.x / nMt;
  const int row0 = tm * BM, col0 = tn * BN;
  const int tid = threadIdx.x;
  const int l = tid & 63, w = tid >> 6;
  const int wr = (w >> 1) * 64, wc = (w & 1) * 64;
  const int lr = l & 15, lk = (l >> 4) * 8;
  f32x4 acc[4][4] = {};
  for (int kt = 0; kt < K; kt += BK) {
    __syncthreads();
#pragma unroll
    for (int i = 0; i < 2; ++i) {
      int c = tid + i * 256;          // 16B chunk id, 512 per tile
      int r = c >> 2;
      int ce = (c & 3) * 8;
      int gr = row0 + r; gr = gr < M ? gr : M - 1;
      bf16x8 va = *(const bf16x8*)(A + (size_t)gr * K + kt + ce);
      *(bf16x8*)&As[r * LSTR + ce] = va;
      bf16x8 vb = *(const bf16x8*)(BT + (size_t)(col0 + r) * K + kt + ce);
      *(bf16x8*)&Bs[r * LSTR + ce] = vb;
    }
    __syncthreads();
    bf16x8 af[4], bfr[4];
#pragma unroll
    for (int m = 0; m < 4; ++m)
      af[m] = *(const bf16x8*)&As[(wr + m * 16 + lr) * LSTR + lk];
#pragma unroll
    for (int n = 0; n < 4; ++n)
      bfr[n] = *(const bf16x8*)&Bs[(wc + n * 16 + lr) * LSTR + lk];
#pragma unroll
    for (int m = 0; m < 4; ++m)
#pragma unroll
      for (int n = 0; n < 4; ++n)
        acc[m][n] = __builtin_amdgcn_mfma_f32_16x16x32_bf16(af[m], bfr[n], acc[m][n], 0, 0, 0);
  }
  const int orow = (l >> 4) * 4;
#pragma unroll
  for (int m = 0; m < 4; ++m)
#pragma unroll
    for (int n = 0; n < 4; ++n)
#pragma unroll
      for (int r = 0; r < 4; ++r) {
        int row = row0 + wr + m * 16 + orow + r;
        int col = col0 + wc + n * 16 + lr;
        if (row < M) C[(size_t)row * N + col] = acc[m][n][r];
      }
}

// ---------------- QKV epilogue: rmsnorm + rope + layouts ----------------
__global__ __launch_bounds__(256) void qkv_epilogue(const float* __restrict__ QKV,
    const int* __restrict__ pos_ids, const int* __restrict__ ghp, const int* __restrict__ gwp,
    const float* __restrict__ qw, const float* __restrict__ kw,
    unsigned short* __restrict__ Qb, unsigned short* __restrict__ Kb,
    unsigned short* __restrict__ Vt) {
  int tok = blockIdx.x * 4 + (threadIdx.x >> 6);
  int l = threadIdx.x & 63;
  if (tok >= B_ * S_) return;
  int b = tok / S_, s = tok % S_;
  const float* rowp = QKV + (size_t)tok * 1280;
  bool rot = (s > 0);
  float cs = 1.f, sn = 0.f;
  if (rot) {
    int gh = ghp[0], gw = gwp[0];
    int pos = pos_ids[tok];
    int hi = (pos / gw) % gh;
    int wi = pos % gw;
    int pi = l >> 1;
    int j = pi < 16 ? pi : pi - 16;
    float invf = exp2f(-(float)j * (13.287712379549449f / 16.f)); // 10000^(-j/16)
    float ang = (pi < 16 ? (float)hi : (float)wi) * invf;
    cs = cosf(ang); sn = sinf(ang);
  }
#pragma unroll
  for (int h = 0; h < H_; ++h) {
    float x = rowp[h * 64 + l];
    float ss = x * x;
    for (int off = 32; off; off >>= 1) ss += __shfl_xor(ss, off);
    float xn = x * rsqrtf(ss * (1.f / 64.f) + EPS_) * qw[l];
    float o = xn;
    if (rot) {
      float p = __shfl_xor(xn, 1);
      o = (l & 1) ? (p * sn + xn * cs) : (xn * cs - p * sn);
    }
    o *= SCALE_;
    Qb[((size_t)(b * H_ + h) * S_ + s) * 64 + l] = f2bf(o);
  }
#pragma unroll
  for (int h = 0; h < KV_; ++h) {
    float x = rowp[768 + h * 64 + l];
    float ss = x * x;
    for (int off = 32; off; off >>= 1) ss += __shfl_xor(ss, off);
    float xn = x * rsqrtf(ss * (1.f / 64.f) + EPS_) * kw[l];
    float o = xn;
    if (rot) {
      float p = __shfl_xor(xn, 1);
      o = (l & 1) ? (p * sn + xn * cs) : (xn * cs - p * sn);
    }
    Kb[((size_t)(b * KV_ + h) * S_ + s) * 64 + l] = f2bf(o);
    float v = rowp[1024 + h * 64 + l];
    Vt[((size_t)(b * KV_ + h) * 64 + l) * SKP + s] = f2bf(v);
  }
}

// ---------------- fused attention ----------------
// block = (b, h, QBLK=8 q-rows); 4 waves; scores fp32 in dyn LDS [8][SCS] (34.9KB -> 4 blk/CU)
__global__ __launch_bounds__(256) void attn_kernel(const unsigned short* __restrict__ Qb,
    const unsigned short* __restrict__ Kb, const unsigned short* __restrict__ Vt,
    unsigned short* __restrict__ ctx, float* __restrict__ attn_out) {
  extern __shared__ float Sc[];
  int bid = blockIdx.x;
  int qt = bid % NQT;
  int h = (bid / NQT) % H_;
  int b = bid / (NQT * H_);
  int kvh = h / NREP;
  int q0 = qt * QBLK;
  int tid = threadIdx.x;
  int l = tid & 63, w = tid >> 6;
  int lr = l & 15, lk = (l >> 4) * 8;

  const unsigned short* Qbase = Qb + (size_t)(b * H_ + h) * S_ * 64;
  const unsigned short* Kbase = Kb + (size_t)(b * KV_ + kvh) * S_ * 64;
  const unsigned short* Vbase = Vt + (size_t)(b * KV_ + kvh) * 64 * SKP;

  // Q fragments (scale pre-folded into Q); rows >= QBLK are dummies (clamped)
  int qrow = q0 + lr; if (qrow >= S_) qrow = S_ - 1;
  bf16x8 qf0 = *(const bf16x8*)(Qbase + (size_t)qrow * 64 + lk);
  bf16x8 qf1 = *(const bf16x8*)(Qbase + (size_t)qrow * 64 + 32 + lk);

  // Phase 1: QK^T with K prefetch. wave w covers keys w*16 within each 64-key tile.
  int kbase = w * 16 + lr;
  {
    const unsigned short* kp = Kbase + (size_t)kbase * 64;  // kt=0: kbase<64<S_
    bf16x8 kf0 = *(const bf16x8*)(kp + lk);
    bf16x8 kf1 = *(const bf16x8*)(kp + 32 + lk);
    for (int kt = 0; kt < NKT; ++kt) {
      bf16x8 nf0 = kf0, nf1 = kf1;
      if (kt + 1 < NKT) {
        int kr = (kt + 1) * 64 + kbase; if (kr >= S_) kr = S_ - 1;
        const unsigned short* np = Kbase + (size_t)kr * 64;
        nf0 = *(const bf16x8*)(np + lk);
        nf1 = *(const bf16x8*)(np + 32 + lk);
      }
      f32x4 acc = {};
      acc = __builtin_amdgcn_mfma_f32_16x16x32_bf16(qf0, kf0, acc, 0, 0, 0);
      acc = __builtin_amdgcn_mfma_f32_16x16x32_bf16(qf1, kf1, acc, 0, 0, 0);
      if (l < 32) {                       // only out-rows 0..7 are real
        int col = kt * 64 + w * 16 + lr;
        int rowb = (l >> 4) * 4;
#pragma unroll
        for (int r = 0; r < 4; ++r) Sc[(size_t)(rowb + r) * SCS + col] = acc[r];
      }
      kf0 = nf0; kf1 = nf1;
    }
  }
  __syncthreads();

  // Phase 2: softmax rows {w, w+4}; vectorized; write attn fp32 to global + bf16 P to LDS
#pragma unroll
  for (int rr = 0; rr < 2; ++rr) {
    int rowi = w + rr * 4;
    int q = q0 + rowi;
    float* srow = Sc + (size_t)rowi * SCS;
    f32x4 v0 = *(const f32x4*)(srow + l * 4);
    f32x4 v1 = *(const f32x4*)(srow + l * 4 + 256);
    f32x4 v2 = *(const f32x4*)(srow + l * 4 + 512);
    f32x4 v3 = *(const f32x4*)(srow + l * 4 + 768);
    float tail = srow[1024];                  // broadcast read
    if (l != 0) tail = -1e30f;                // only lane0's tail (key 1024) is real
    float mx = tail;
#pragma unroll
    for (int c = 0; c < 4; ++c) { mx = fmaxf(mx, v0[c]); mx = fmaxf(mx, v1[c]); mx = fmaxf(mx, v2[c]); mx = fmaxf(mx, v3[c]); }
    for (int off = 32; off; off >>= 1) mx = fmaxf(mx, __shfl_xor(mx, off));
    float sum = 0.f;
#pragma unroll
    for (int c = 0; c < 4; ++c) {
      v0[c] = __expf(v0[c] - mx); sum += v0[c];
      v1[c] = __expf(v1[c] - mx); sum += v1[c];
      v2[c] = __expf(v2[c] - mx); sum += v2[c];
      v3[c] = __expf(v3[c] - mx); sum += v3[c];
    }
    float te = __expf(tail - mx); sum += te;  // 0 for l!=0
    for (int off = 32; off; off >>= 1) sum += __shfl_xor(sum, off);
    float inv = 1.f / sum;
#pragma unroll
    for (int c = 0; c < 4; ++c) { v0[c] *= inv; v1[c] *= inv; v2[c] *= inv; v3[c] *= inv; }
    te *= inv;
    if (q < S_) {
      float* gout = attn_out + ((size_t)(b * H_ + h) * S_ + q) * S_;
      *(f32x4*)(gout + l * 4)       = v0;
      *(f32x4*)(gout + l * 4 + 256) = v1;
      *(f32x4*)(gout + l * 4 + 512) = v2;
      *(f32x4*)(gout + l * 4 + 768) = v3;
      if (l == 0) gout[1024] = te;
    }
    // bf16 P write-back (in-place alias; all reads of this row completed above)
    unsigned short* urow = (unsigned short*)srow;
    uint2 o0, o1;
    o0.x = pk2(v0[0], v0[1]); o0.y = pk2(v0[2], v0[3]);
    o1.x = pk2(v1[0], v1[1]); o1.y = pk2(v1[2], v1[3]);
    *(uint2*)&urow[l * 4]       = o0;
    *(uint2*)&urow[l * 4 + 256] = o1;
    o0.x = pk2(v2[0], v2[1]); o0.y = pk2(v2[2], v2[3]);
    o1.x = pk2(v3[0], v3[1]); o1.y = pk2(v3[2], v3[3]);
    *(uint2*)&urow[l * 4 + 512] = o0;
    *(uint2*)&urow[l * 4 + 768] = o1;
    urow[1024 + l] = f2bf(te);               // lanes 1..63 write 0 -> zero pads
  }
  __syncthreads();

  // Phase 3: PV, P read as bf16 from LDS. wave w owns d-range [w*16, w*16+16).
  f32x4 accv = {};
  const unsigned short* U = (const unsigned short*)Sc;
  const int prow = (lr & 7) * (SCS * 2);     // rows 8..15 duplicate 0..7 (discarded)
  const unsigned short* vb = Vbase + (size_t)(w * 16 + lr) * SKP;
  for (int kc = 0; kc < SKP / 32; ++kc) {
    bf16x8 pa = *(const bf16x8*)&U[prow + kc * 32 + lk];
    bf16x8 vf = *(const bf16x8*)(vb + kc * 32 + lk);
    accv = __builtin_amdgcn_mfma_f32_16x16x32_bf16(pa, vf, accv, 0, 0, 0);
  }
  if (l < 32) {
    int rowb = (l >> 4) * 4;
#pragma unroll
    for (int r = 0; r < 4; ++r) {
      int q = q0 + rowb + r;
      if (q < S_)
        ctx[(size_t)(b * S_ + q) * 768 + h * 64 + w * 16 + lr] = f2bf(accv[r]);
    }
  }
}

// ---------------- launch ----------------
extern "C" void kernel_launch(void* const* d_in, const int* in_sizes, int n_in,
                              void* d_out, int out_size, void* d_ws, size_t ws_size,
                              hipStream_t stream) {
  const float* hidden = (const float*)d_in[0];
  const int* pos_ids = (const int*)d_in[2];
  const int* ghp = (const int*)d_in[3];
  const int* gwp = (const int*)d_in[4];
  const float* Wq = (const float*)d_in[5];
  const float* Wk = (const float*)d_in[6];
  const float* Wv = (const float*)d_in[7];
  const float* Wo = (const float*)d_in[8];
  const float* qnw = (const float*)d_in[9];
  const float* knw = (const float*)d_in[10];

  char* ws = (char*)d_ws;
  unsigned short* Xb    = (unsigned short*)ws;                   // 12,595,200
  unsigned short* WqkvT = (unsigned short*)(ws + 12595200);      //  1,966,080
  unsigned short* WoT   = (unsigned short*)(ws + 14561280);      //  1,179,648
  float*          QKV   = (float*)(ws + 15740928);               // 41,984,000
  unsigned short* ctx   = (unsigned short*)(ws + 15740928);      // alias (after QKV consumed)
  unsigned short* Qb    = (unsigned short*)(ws + 57724928);      // 12,595,200
  unsigned short* Kb    = (unsigned short*)(ws + 70320128);      //  4,198,400
  unsigned short* Vt    = (unsigned short*)(ws + 74518528);      //  4,456,448

  float* out0 = (float*)d_out;
  float* attn_out = out0 + (size_t)B_ * S_ * D_;

  cast_x_kernel<<<6150, 256, 0, stream>>>(hidden, Xb, 1574400);
  cast_wqkv_kernel<<<3840, 256, 0, stream>>>(Wq, Wk, Wv, WqkvT);
  cast_wo_kernel<<<2304, 256, 0, stream>>>(Wo, WoT);

  gemm_bt<<<65 * 10, 256, 0, stream>>>(Xb, WqkvT, QKV, B_ * S_, 1280, D_);

  qkv_epilogue<<<2050, 256, 0, stream>>>(QKV, pos_ids, ghp, gwp, qnw, knw, Qb, Kb, Vt);

  hipFuncSetAttribute((const void*)attn_kernel,
                      hipFuncAttributeMaxDynamicSharedMemorySize, QBLK * SCS * 4);
  attn_kernel<<<B_ * H_ * NQT, 256, QBLK * SCS * 4, stream>>>(Qb, Kb, Vt, ctx, attn_out);

  gemm_bt<<<65 * 6, 256, 0, stream>>>(ctx, WoT, out0, B_ * S_, D_, D_);
}

// Round 3
// 351.932 us; speedup vs baseline: 1.4527x; 1.4527x over previous
//
#include <hip/hip_runtime.h>

#define B_ 8
#define S_ 1025
#define D_ 768
#define H_ 12
#define KV_ 4
#define HD_ 64
#define NREP 3
#define SCALE_ 0.125f
#define EPS_ 1e-6f
#define SKP 1088   // padded key count (17*64)
#define SCS 1092   // LDS score row stride in floats
#define QBLK 16    // q-rows per block
#define NQT 65     // ceil(1025/16)

typedef __attribute__((ext_vector_type(8))) short bf16x8;
typedef __attribute__((ext_vector_type(4))) float f32x4;

__device__ __forceinline__ unsigned short f2bf(float f) {
  unsigned int u = __builtin_bit_cast(unsigned int, f);
  return (unsigned short)((u + 0x7FFFu + ((u >> 16) & 1u)) >> 16);
}
__device__ __forceinline__ unsigned int pk2(float a, float b) {
  return (unsigned int)f2bf(a) | ((unsigned int)f2bf(b) << 16);
}

// ---------------- casts ----------------
__global__ __launch_bounds__(256) void cast_x_kernel(const float* __restrict__ x,
                                                     unsigned short* __restrict__ xb, int n4) {
  int i = blockIdx.x * 256 + threadIdx.x;
  if (i >= n4) return;
  f32x4 v = *(const f32x4*)(x + (size_t)i * 4);
  uint2 o;
  o.x = pk2(v[0], v[1]);
  o.y = pk2(v[2], v[3]);
  *(uint2*)(xb + (size_t)i * 4) = o;
}

__global__ __launch_bounds__(256) void cast_wqkv_kernel(const float* __restrict__ Wq,
    const float* __restrict__ Wk, const float* __restrict__ Wv,
    unsigned short* __restrict__ WT) {
  int idx = blockIdx.x * 256 + threadIdx.x;  // = n*768 + k
  int n = idx / D_, k = idx % D_;
  float v;
  if (n < 768)       v = Wq[(size_t)k * 768 + n];
  else if (n < 1024) v = Wk[(size_t)k * 256 + (n - 768)];
  else               v = Wv[(size_t)k * 256 + (n - 1024)];
  WT[idx] = f2bf(v);
}

__global__ __launch_bounds__(256) void cast_wo_kernel(const float* __restrict__ Wo,
                                                      unsigned short* __restrict__ WT) {
  int idx = blockIdx.x * 256 + threadIdx.x;  // = n*768 + k
  int n = idx / D_, k = idx % D_;
  WT[idx] = f2bf(Wo[(size_t)k * D_ + n]);
}

// ---------------- GEMM: C[M][N] fp32 = A[M][K] bf16 @ BT[N][K] bf16 ----------------
#define BM 128
#define BN 128
#define BK 32
#define LSTR 40   // padded LDS row stride (ushorts)
__global__ __launch_bounds__(256) void gemm_bt(const unsigned short* __restrict__ A,
    const unsigned short* __restrict__ BT, float* __restrict__ C, int M, int N, int K) {
  __shared__ unsigned short As[BM * LSTR];
  __shared__ unsigned short Bs[BN * LSTR];
  const int nMt = (M + BM - 1) / BM;
  const int tm = blockIdx.x % nMt;
  const int tn = blockIdx.x / nMt;
  const int row0 = tm * BM, col0 = tn * BN;
  const int tid = threadIdx.x;
  const int l = tid & 63, w = tid >> 6;
  const int wr = (w >> 1) * 64, wc = (w & 1) * 64;
  const int lr = l & 15, lk = (l >> 4) * 8;
  f32x4 acc[4][4] = {};
  for (int kt = 0; kt < K; kt += BK) {
    __syncthreads();
#pragma unroll
    for (int i = 0; i < 2; ++i) {
      int c = tid + i * 256;
      int r = c >> 2;
      int ce = (c & 3) * 8;
      int gr = row0 + r; gr = gr < M ? gr : M - 1;
      bf16x8 va = *(const bf16x8*)(A + (size_t)gr * K + kt + ce);
      *(bf16x8*)&As[r * LSTR + ce] = va;
      bf16x8 vb = *(const bf16x8*)(BT + (size_t)(col0 + r) * K + kt + ce);
      *(bf16x8*)&Bs[r * LSTR + ce] = vb;
    }
    __syncthreads();
    bf16x8 af[4], bfr[4];
#pragma unroll
    for (int m = 0; m < 4; ++m)
      af[m] = *(const bf16x8*)&As[(wr + m * 16 + lr) * LSTR + lk];
#pragma unroll
    for (int n = 0; n < 4; ++n)
      bfr[n] = *(const bf16x8*)&Bs[(wc + n * 16 + lr) * LSTR + lk];
#pragma unroll
    for (int m = 0; m < 4; ++m)
#pragma unroll
      for (int n = 0; n < 4; ++n)
        acc[m][n] = __builtin_amdgcn_mfma_f32_16x16x32_bf16(af[m], bfr[n], acc[m][n], 0, 0, 0);
  }
  const int orow = (l >> 4) * 4;
#pragma unroll
  for (int m = 0; m < 4; ++m)
#pragma unroll
    for (int n = 0; n < 4; ++n)
#pragma unroll
      for (int r = 0; r < 4; ++r) {
        int row = row0 + wr + m * 16 + orow + r;
        int col = col0 + wc + n * 16 + lr;
        if (row < M) C[(size_t)row * N + col] = acc[m][n][r];
      }
}

// ---------------- QKV epilogue: rmsnorm + rope + layouts ----------------
__global__ __launch_bounds__(256) void qkv_epilogue(const float* __restrict__ QKV,
    const int* __restrict__ pos_ids, const int* __restrict__ ghp, const int* __restrict__ gwp,
    const float* __restrict__ qw, const float* __restrict__ kw,
    unsigned short* __restrict__ Qb, unsigned short* __restrict__ Kb,
    unsigned short* __restrict__ Vt) {
  int tok = blockIdx.x * 4 + (threadIdx.x >> 6);
  int l = threadIdx.x & 63;
  if (tok >= B_ * S_) return;
  int b = tok / S_, s = tok % S_;
  const float* rowp = QKV + (size_t)tok * 1280;
  bool rot = (s > 0);
  float cs = 1.f, sn = 0.f;
  if (rot) {
    int gh = ghp[0], gw = gwp[0];
    int pos = pos_ids[tok];
    int hi = (pos / gw) % gh;
    int wi = pos % gw;
    int pi = l >> 1;
    int j = pi < 16 ? pi : pi - 16;
    float invf = exp2f(-(float)j * (13.287712379549449f / 16.f)); // 10000^(-j/16)
    float ang = (pi < 16 ? (float)hi : (float)wi) * invf;
    cs = cosf(ang); sn = sinf(ang);
  }
#pragma unroll
  for (int h = 0; h < H_; ++h) {
    float x = rowp[h * 64 + l];
    float ss = x * x;
    for (int off = 32; off; off >>= 1) ss += __shfl_xor(ss, off);
    float xn = x * rsqrtf(ss * (1.f / 64.f) + EPS_) * qw[l];
    float o = xn;
    if (rot) {
      float p = __shfl_xor(xn, 1);
      o = (l & 1) ? (p * sn + xn * cs) : (xn * cs - p * sn);
    }
    o *= SCALE_;
    Qb[((size_t)(b * H_ + h) * S_ + s) * 64 + l] = f2bf(o);
  }
#pragma unroll
  for (int h = 0; h < KV_; ++h) {
    float x = rowp[768 + h * 64 + l];
    float ss = x * x;
    for (int off = 32; off; off >>= 1) ss += __shfl_xor(ss, off);
    float xn = x * rsqrtf(ss * (1.f / 64.f) + EPS_) * kw[l];
    float o = xn;
    if (rot) {
      float p = __shfl_xor(xn, 1);
      o = (l & 1) ? (p * sn + xn * cs) : (xn * cs - p * sn);
    }
    Kb[((size_t)(b * KV_ + h) * S_ + s) * 64 + l] = f2bf(o);
    float v = rowp[1024 + h * 64 + l];
    Vt[((size_t)(b * KV_ + h) * 64 + l) * SKP + s] = f2bf(v);
  }
}

// ---------------- fused attention ----------------
// block = (b, h, 16 q-rows); 8 waves (512 thr); scores fp32 in dyn LDS [16][SCS]
// 69.9KB dyn + 4KB static partials -> 2 blocks/CU -> 16 waves/CU.
__global__ __launch_bounds__(512) void attn_kernel(const unsigned short* __restrict__ Qb,
    const unsigned short* __restrict__ Kb, const unsigned short* __restrict__ Vt,
    unsigned short* __restrict__ ctx, float* __restrict__ attn_out) {
  extern __shared__ float Sc[];
  __shared__ float partial[4][64][4];
  // bijective XCD swizzle: 6240 blocks = 8 * 780
  int bid = blockIdx.x;
  int swz = (bid & 7) * 780 + (bid >> 3);
  int qt = swz % NQT;
  int h = (swz / NQT) % H_;
  int b = swz / (NQT * H_);
  int kvh = h / NREP;
  int q0 = qt * QBLK;
  int tid = threadIdx.x;
  int l = tid & 63, w = tid >> 6;          // w in [0,8)
  int lr = l & 15, lk = (l >> 4) * 8;

  const unsigned short* Qbase = Qb + (size_t)(b * H_ + h) * S_ * 64;
  const unsigned short* Kbase = Kb + (size_t)(b * KV_ + kvh) * S_ * 64;
  const unsigned short* Vbase = Vt + (size_t)(b * KV_ + kvh) * 64 * SKP;

  // Q fragments (scale pre-folded)
  int qrow = q0 + lr; if (qrow >= S_) qrow = S_ - 1;
  bf16x8 qf0 = *(const bf16x8*)(Qbase + (size_t)qrow * 64 + lk);
  bf16x8 qf1 = *(const bf16x8*)(Qbase + (size_t)qrow * 64 + 32 + lk);

  // Phase 1: QK^T. sweep t covers keys t*128 + w*16; sweep 8 only waves 0-3 (keys 1024..1087).
  {
    const int kcol = w * 16 + lr;
    const int nT = (w < 4) ? 9 : 8;
    const unsigned short* kp = Kbase + (size_t)kcol * 64;   // t=0: kcol<128 valid
    bf16x8 kf0 = *(const bf16x8*)(kp + lk);
    bf16x8 kf1 = *(const bf16x8*)(kp + 32 + lk);
    for (int t = 0; t < nT; ++t) {
      bf16x8 nf0 = kf0, nf1 = kf1;
      if (t + 1 < nT) {
        int kr = (t + 1) * 128 + kcol; if (kr >= S_) kr = S_ - 1;
        const unsigned short* np = Kbase + (size_t)kr * 64;
        nf0 = *(const bf16x8*)(np + lk);
        nf1 = *(const bf16x8*)(np + 32 + lk);
      }
      f32x4 acc = {};
      acc = __builtin_amdgcn_mfma_f32_16x16x32_bf16(qf0, kf0, acc, 0, 0, 0);
      acc = __builtin_amdgcn_mfma_f32_16x16x32_bf16(qf1, kf1, acc, 0, 0, 0);
      int col = t * 128 + kcol;            // <= 1087 by construction
      int rowb = (l >> 4) * 4;
#pragma unroll
      for (int r = 0; r < 4; ++r) Sc[(size_t)(rowb + r) * SCS + col] = acc[r];
      kf0 = nf0; kf1 = nf1;
    }
  }
  __syncthreads();

  // Phase 2: softmax rows {w, w+8}; coalesced nt dword stores; bf16 P writeback to LDS.
#pragma unroll
  for (int rr = 0; rr < 2; ++rr) {
    int rowi = w + rr * 8;
    int q = q0 + rowi;
    float* srow = Sc + (size_t)rowi * SCS;
    float vals[17];
    float mx = -1e30f;
#pragma unroll
    for (int i = 0; i < 17; ++i) {
      int key = l + i * 64;
      float v = (key < S_) ? srow[key] : -1e30f;
      vals[i] = v;
      mx = fmaxf(mx, v);
    }
    for (int off = 32; off; off >>= 1) mx = fmaxf(mx, __shfl_xor(mx, off));
    float sum = 0.f;
#pragma unroll
    for (int i = 0; i < 17; ++i) {
      float e = __expf(vals[i] - mx);
      vals[i] = e; sum += e;
    }
    for (int off = 32; off; off >>= 1) sum += __shfl_xor(sum, off);
    float inv = 1.f / sum;
    if (q < S_) {
      float* gout = attn_out + ((size_t)(b * H_ + h) * S_ + q) * S_;
#pragma unroll
      for (int i = 0; i < 17; ++i) {
        int key = l + i * 64;
        if (key < S_) __builtin_nontemporal_store(vals[i] * inv, gout + key);
      }
    }
    unsigned short* urow = (unsigned short*)srow;
#pragma unroll
    for (int i = 0; i < 17; ++i) {
      int key = l + i * 64;
      float p = (key < S_) ? vals[i] * inv : 0.f;
      urow[key] = f2bf(p);                 // zero pads for PV
    }
  }
  __syncthreads();

  // Phase 3: PV. wave w: d-block (w&3)*16, key-half (w>>2)*544; 17 kc steps of 32.
  f32x4 accv = {};
  {
    const int d0 = (w & 3) * 16;
    const int kh = (w >> 2) * 544;
    const unsigned short* U = (const unsigned short*)Sc;
    const int prow = lr * (SCS * 2);
    const unsigned short* vb = Vbase + (size_t)(d0 + lr) * SKP + kh;
#pragma unroll 4
    for (int kc = 0; kc < 17; ++kc) {
      bf16x8 pa = *(const bf16x8*)&U[prow + kh + kc * 32 + lk];
      bf16x8 vf = *(const bf16x8*)(vb + kc * 32 + lk);
      accv = __builtin_amdgcn_mfma_f32_16x16x32_bf16(pa, vf, accv, 0, 0, 0);
    }
  }
  if (w >= 4) *(f32x4*)partial[w - 4][l] = accv;
  __syncthreads();
  if (w < 4) {
    accv += *(const f32x4*)partial[w][l];
    int rowb = (l >> 4) * 4;
    int d0 = (w & 3) * 16;
#pragma unroll
    for (int r = 0; r < 4; ++r) {
      int q = q0 + rowb + r;
      if (q < S_)
        ctx[(size_t)(b * S_ + q) * 768 + h * 64 + d0 + lr] = f2bf(accv[r]);
    }
  }
}

// ---------------- launch ----------------
extern "C" void kernel_launch(void* const* d_in, const int* in_sizes, int n_in,
                              void* d_out, int out_size, void* d_ws, size_t ws_size,
                              hipStream_t stream) {
  const float* hidden = (const float*)d_in[0];
  const int* pos_ids = (const int*)d_in[2];
  const int* ghp = (const int*)d_in[3];
  const int* gwp = (const int*)d_in[4];
  const float* Wq = (const float*)d_in[5];
  const float* Wk = (const float*)d_in[6];
  const float* Wv = (const float*)d_in[7];
  const float* Wo = (const float*)d_in[8];
  const float* qnw = (const float*)d_in[9];
  const float* knw = (const float*)d_in[10];

  char* ws = (char*)d_ws;
  unsigned short* Xb    = (unsigned short*)ws;                   // 12,595,200
  unsigned short* WqkvT = (unsigned short*)(ws + 12595200);      //  1,966,080
  unsigned short* WoT   = (unsigned short*)(ws + 14561280);      //  1,179,648
  float*          QKV   = (float*)(ws + 15740928);               // 41,984,000
  unsigned short* ctx   = (unsigned short*)(ws + 15740928);      // alias (after QKV consumed)
  unsigned short* Qb    = (unsigned short*)(ws + 57724928);      // 12,595,200
  unsigned short* Kb    = (unsigned short*)(ws + 70320128);      //  4,198,400
  unsigned short* Vt    = (unsigned short*)(ws + 74518528);      //  4,456,448

  float* out0 = (float*)d_out;
  float* attn_out = out0 + (size_t)B_ * S_ * D_;

  cast_x_kernel<<<6150, 256, 0, stream>>>(hidden, Xb, 1574400);
  cast_wqkv_kernel<<<3840, 256, 0, stream>>>(Wq, Wk, Wv, WqkvT);
  cast_wo_kernel<<<2304, 256, 0, stream>>>(Wo, WoT);

  gemm_bt<<<65 * 10, 256, 0, stream>>>(Xb, WqkvT, QKV, B_ * S_, 1280, D_);

  hipMemsetAsync(Vt, 0, 4456448, stream);
  qkv_epilogue<<<2050, 256, 0, stream>>>(QKV, pos_ids, ghp, gwp, qnw, knw, Qb, Kb, Vt);

  hipFuncSetAttribute((const void*)attn_kernel,
                      hipFuncAttributeMaxDynamicSharedMemorySize, QBLK * SCS * 4);
  attn_kernel<<<B_ * H_ * NQT, 512, QBLK * SCS * 4, stream>>>(Qb, Kb, Vt, ctx, attn_out);

  gemm_bt<<<65 * 6, 256, 0, stream>>>(ctx, WoT, out0, B_ * S_, D_, D_);
}